// Round 1
// baseline (317.364 us; speedup 1.0000x reference)
//
#include <hip/hip_runtime.h>

// ReservoirSampler: last-write-wins scatter (atomicMax over sample index per
// slot) + row gather. D = 256 floats/row.
//
// winner[j] = max sample index p targeting slot j, or -1 if untouched.
// Fill phase (pos < n) and reservoir phase both expressed as atomicMax against
// a -1-initialized array -> single scatter kernel, order-independent.

#define D_FEAT 256
#define F4_PER_ROW (D_FEAT / 4)  // 64 float4 per row

__global__ void rs_scatter(const float* __restrict__ u,
                           const int* __restrict__ i0_ptr,
                           int* __restrict__ winner,
                           int b, int n) {
    int p = blockIdx.x * blockDim.x + threadIdx.x;
    if (p >= b) return;
    const int i0 = *i0_ptr;            // scalar broadcast load
    const int pos = i0 + p;
    int idx;
    if (pos < n) {
        idx = pos;                      // deterministic fill
    } else {
        // randint(0, pos) inclusive == floor(u * (pos+1)), clipped for u->1.
        // pos+1 <= ~2.7e5 < 2^24: exact in f32; multiply is RN -> bit-matches numpy.
        float r = floorf(u[p] * (float)(pos + 1));
        int ri = (int)r;
        if (ri > pos) ri = pos;
        if (ri >= n) return;            // rejected sample
        idx = ri;
    }
    atomicMax(&winner[idx], p);         // device-scope, cross-XCD safe
}

__global__ void rs_gather(const float4* __restrict__ samples,
                          const float4* __restrict__ buffer,
                          const int* __restrict__ winner,
                          float4* __restrict__ out) {
    // 256 threads/block = 4 rows, one 64-lane wave per row; 16 B/lane = 1 KiB row.
    const int row  = blockIdx.x * 4 + (threadIdx.x >> 6);
    const int lane = threadIdx.x & 63;
    const int w = winner[row];          // wave-uniform broadcast
    const float4* __restrict__ src =
        (w >= 0) ? (samples + (size_t)w * F4_PER_ROW)
                 : (buffer  + (size_t)row * F4_PER_ROW);
    out[(size_t)row * F4_PER_ROW + lane] = src[lane];
}

extern "C" void kernel_launch(void* const* d_in, const int* in_sizes, int n_in,
                              void* d_out, int out_size, void* d_ws, size_t ws_size,
                              hipStream_t stream) {
    const float* samples = (const float*)d_in[0];
    const float* buffer  = (const float*)d_in[1];
    const float* u       = (const float*)d_in[2];
    const int*   i0_ptr  = (const int*)d_in[3];
    float*       out     = (float*)d_out;

    const int b = in_sizes[0] / D_FEAT;   // 262144
    const int n = in_sizes[1] / D_FEAT;   // 16384

    int* winner = (int*)d_ws;             // n int32 = 64 KiB scratch

    // 1) winner[:] = -1 (0xFF bytes). Graph-capture-safe async memset.
    hipMemsetAsync(winner, 0xFF, (size_t)n * sizeof(int), stream);

    // 2) scatter: one thread per incoming sample.
    rs_scatter<<<(b + 255) / 256, 256, 0, stream>>>(u, i0_ptr, winner, b, n);

    // 3) gather: 4 rows per 256-thread block.
    rs_gather<<<n / 4, 256, 0, stream>>>((const float4*)samples,
                                         (const float4*)buffer,
                                         winner, (float4*)out);
}